// Round 8
// baseline (41.950 us; speedup 1.0000x reference)
//
#include <hip/hip_runtime.h>
#include <math.h>

#define NQ 4
#define DIN 256
#define DOUT 64
#define NLAYER 2
#define TPB 256
#define WROWS 32            // rows per wave; block = 4 waves = 128 rows; grid = 1024
#define NIT (WROWS/2)       // 16 iterations, 2 rows per wave-iteration
#define PF 3                // prefetch depth (iterations ahead)

__device__ __forceinline__ float tanh_fast(float y) {
    float e = __expf(2.0f * y);
    return 1.0f - 2.0f / (e + 1.0f);
}

__global__ __launch_bounds__(TPB, 4) void qp_fused(
    const float* __restrict__ x,  const float* __restrict__ W1,
    const float* __restrict__ b1, const float* __restrict__ wts,
    const float* __restrict__ W2, const float* __restrict__ b2,
    float* __restrict__ out)
{
    __shared__ __align__(16) float fs[4][WROWS][NQ];  // wave-private f tiles
    __shared__ __align__(16) float qs[4][WROWS][NQ];  // wave-private q tiles
    __shared__ __align__(16) float w2s[DOUT][NQ];     // 1 KB
    __shared__ __align__(16) float us[8][8];          // Rot gates
    __shared__ float b2s[DOUT];

    const int t = threadIdx.x;
    const int wave = t >> 6, lane = t & 63;
    const int half = lane >> 5;          // which of the wave's 2 rows per iter
    const int cl   = lane & 31;          // float4 chunk index within row half
    const int qsel = lane & 3;

    // ---- stage shared constants; the ONLY block-wide barrier
    if (t < 64) {
        ((float4*)&w2s[0][0])[t] = ((const float4*)W2)[t];
        b2s[t] = b2[t];
    }
    if (t < 8) {
        const float phi = wts[t*3 + 0], th = wts[t*3 + 1], om = wts[t*3 + 2];
        float sth, cth; sincosf(0.5f*th, &sth, &cth);
        float sp, cp;   sincosf(0.5f*(phi+om), &sp, &cp);
        float sm, cm;   sincosf(0.5f*(phi-om), &sm, &cm);
        us[t][0] =  cth*cp; us[t][1] = -cth*sp;
        us[t][2] = -sth*cm; us[t][3] = -sth*sm;
        us[t][4] =  sth*cm; us[t][5] = -sth*sm;
        us[t][6] =  cth*cp; us[t][7] =  cth*sp;
    }
    __syncthreads();

    const int wrow = (blockIdx.x * 4 + wave) * WROWS;  // wave's first row
    float (* __restrict__ fsw)[NQ] = fs[wave];
    float (* __restrict__ qsw)[NQ] = qs[wave];

    // ---- phase 1: f = pi*tanh(x@W1^T+b1); 32 lanes/row; barrier-free
    {
        float4 w[4][2];
        #pragma unroll
        for (int q = 0; q < 4; ++q) {
            w[q][0] = ((const float4*)W1)[q*64 + cl];
            w[q][1] = ((const float4*)W1)[q*64 + 32 + cl];
        }
        const float4 bv = *(const float4*)b1;
        const float bsel = (qsel==0)?bv.x:(qsel==1)?bv.y:(qsel==2)?bv.z:bv.w;

        const int row0 = wrow + half;               // + it*2

        float4 buf[PF+1][2];                        // ring, statically indexed
        #pragma unroll
        for (int k = 0; k < PF; ++k) {
            const float4* xn = (const float4*)(x + (size_t)(row0 + k*2) * DIN);
            buf[k][0] = xn[cl]; buf[k][1] = xn[32 + cl];
        }

        #pragma unroll
        for (int it = 0; it < NIT; ++it) {
            if (it + PF < NIT) {
                const float4* xn = (const float4*)(x + (size_t)(row0 + (it+PF)*2) * DIN);
                buf[(it+PF)&PF][0] = xn[cl];
                buf[(it+PF)&PF][1] = xn[32 + cl];
            }
            const float4 xv0 = buf[it&PF][0];
            const float4 xv1 = buf[it&PF][1];

            float a0, a1, a2, a3;
            a0 = fmaf(xv0.x,w[0][0].x, fmaf(xv0.y,w[0][0].y, fmaf(xv0.z,w[0][0].z, xv0.w*w[0][0].w)));
            a1 = fmaf(xv0.x,w[1][0].x, fmaf(xv0.y,w[1][0].y, fmaf(xv0.z,w[1][0].z, xv0.w*w[1][0].w)));
            a2 = fmaf(xv0.x,w[2][0].x, fmaf(xv0.y,w[2][0].y, fmaf(xv0.z,w[2][0].z, xv0.w*w[2][0].w)));
            a3 = fmaf(xv0.x,w[3][0].x, fmaf(xv0.y,w[3][0].y, fmaf(xv0.z,w[3][0].z, xv0.w*w[3][0].w)));
            a0 = fmaf(xv1.x,w[0][1].x, fmaf(xv1.y,w[0][1].y, fmaf(xv1.z,w[0][1].z, fmaf(xv1.w,w[0][1].w, a0))));
            a1 = fmaf(xv1.x,w[1][1].x, fmaf(xv1.y,w[1][1].y, fmaf(xv1.z,w[1][1].z, fmaf(xv1.w,w[1][1].w, a1))));
            a2 = fmaf(xv1.x,w[2][1].x, fmaf(xv1.y,w[2][1].y, fmaf(xv1.z,w[2][1].z, fmaf(xv1.w,w[2][1].w, a2))));
            a3 = fmaf(xv1.x,w[3][1].x, fmaf(xv1.y,w[3][1].y, fmaf(xv1.z,w[3][1].z, fmaf(xv1.w,w[3][1].w, a3))));

            a0 += __shfl_xor(a0, 1, 64);  a1 += __shfl_xor(a1, 1, 64);
            a2 += __shfl_xor(a2, 1, 64);  a3 += __shfl_xor(a3, 1, 64);
            a0 += __shfl_xor(a0, 2, 64);  a1 += __shfl_xor(a1, 2, 64);
            a2 += __shfl_xor(a2, 2, 64);  a3 += __shfl_xor(a3, 2, 64);
            float v = (qsel==0)?a0:(qsel==1)?a1:(qsel==2)?a2:a3;
            v += __shfl_xor(v, 4, 64);
            v += __shfl_xor(v, 8, 64);
            v += __shfl_xor(v, 16, 64);

            if (cl < 4) {
                const float PI = 3.14159265358979f;
                fsw[it*2 + half][qsel] = PI * tanh_fast(v + bsel);
            }
        }
    }
    // same-wave LDS producer->consumer: compiler inserts lgkmcnt wait; no barrier

    // ---- phase 2: 4-qubit circuit, one row per lane (lanes 0..31)
    if (lane < WROWS) {
        const float4 fv = *(const float4*)fsw[lane];
        const float fq[4] = {fv.x, fv.y, fv.z, fv.w};
        const float IS2 = 0.70710678118654752f;
        float vr[4][2], vi[4][2];
        #pragma unroll
        for (int i = 0; i < 4; ++i) {
            const float fi = fq[i];
            const float f2 = fi*fi;
            const float ca = rsqrtf(1.0f + f2);
            const float ch = sqrtf(0.5f*(1.0f + ca));
            const float sh = copysignf(sqrtf(fmaxf(0.5f*(1.0f - ca), 0.0f)), fi);
            const float cb = rsqrtf(1.0f + f2*f2);
            const float cbh = sqrtf(0.5f*(1.0f + cb));
            const float sbh = sqrtf(fmaxf(0.5f*(1.0f - cb), 0.0f));
            const float u0 = (ch - sh) * IS2;
            const float u1 = (ch + sh) * IS2;
            vr[i][0] = u0 * cbh;  vi[i][0] = -u0 * sbh;
            vr[i][1] = u1 * cbh;  vi[i][1] =  u1 * sbh;
        }
        float ar[16], ai[16];
        #pragma unroll
        for (int i0 = 0; i0 < 2; ++i0)
        #pragma unroll
        for (int i1 = 0; i1 < 2; ++i1) {
            const float pr  = vr[0][i0]*vr[1][i1] - vi[0][i0]*vi[1][i1];
            const float pim = vr[0][i0]*vi[1][i1] + vi[0][i0]*vr[1][i1];
            #pragma unroll
            for (int i2 = 0; i2 < 2; ++i2)
            #pragma unroll
            for (int i3 = 0; i3 < 2; ++i3) {
                const float qr  = vr[2][i2]*vr[3][i3] - vi[2][i2]*vi[3][i3];
                const float qim = vr[2][i2]*vi[3][i3] + vi[2][i2]*vr[3][i3];
                const int idx = i0*8 + i1*4 + i2*2 + i3;
                ar[idx] = pr*qr - pim*qim;
                ai[idx] = pr*qim + pim*qr;
            }
        }
        #pragma unroll
        for (int l = 0; l < NLAYER; ++l) {
            constexpr int cpairs[8][2] = {{0,1},{1,2},{2,3},{3,0},{0,2},{1,3},{2,0},{3,1}};
            #pragma unroll
            for (int g = 0; g < 8; ++g) {
                const int bc = 8 >> cpairs[g][0];
                const int bt = 8 >> cpairs[g][1];
                #pragma unroll
                for (int m = 0; m < 16; ++m) {
                    if ((m & bc) && !(m & bt)) {
                        const int m2 = m | bt;
                        float tr = ar[m]; ar[m] = ar[m2]; ar[m2] = tr;
                        float ti = ai[m]; ai[m] = ai[m2]; ai[m2] = ti;
                    }
                }
            }
            #pragma unroll
            for (int i = 0; i < 4; ++i) {
                const float* u = &us[l*4 + i][0];
                const float u00r=u[0], u00i=u[1], u01r=u[2], u01i=u[3];
                const float u10r=u[4], u10i=u[5], u11r=u[6], u11i=u[7];
                const int bq = 8 >> i;
                #pragma unroll
                for (int m = 0; m < 16; ++m) {
                    if (!(m & bq)) {
                        const int m2 = m | bq;
                        const float a0r=ar[m], a0i=ai[m], a1r=ar[m2], a1i=ai[m2];
                        ar[m]  = u00r*a0r - u00i*a0i + u01r*a1r - u01i*a1i;
                        ai[m]  = u00r*a0i + u00i*a0r + u01r*a1i + u01i*a1r;
                        ar[m2] = u10r*a0r - u10i*a0i + u11r*a1r - u11i*a1i;
                        ai[m2] = u10r*a0i + u10i*a0r + u11r*a1i + u11i*a1r;
                    }
                }
            }
        }
        float z0=0.f, z1=0.f, z2=0.f, z3=0.f;
        #pragma unroll
        for (int m = 0; m < 16; ++m) {
            const float p = ar[m]*ar[m] + ai[m]*ai[m];
            z0 += (m & 8) ? -p : p;
            z1 += (m & 4) ? -p : p;
            z2 += (m & 2) ? -p : p;
            z3 += (m & 1) ? -p : p;
        }
        float4 qv; qv.x=z0; qv.y=z1; qv.z=z2; qv.w=z3;
        *(float4*)qsw[lane] = qv;
    }

    // ---- phase 3: out = q @ W2^T + b2 for this wave's 32 rows, coalesced
    {
        const int j4 = lane & 15;        // output float4-column
        const int rb = lane >> 4;        // 0..3 row subgroup
        float w2r[4][4], b2r[4];
        #pragma unroll
        for (int jj = 0; jj < 4; ++jj) {
            const int j = j4*4 + jj;
            #pragma unroll
            for (int i = 0; i < 4; ++i) w2r[jj][i] = w2s[j][i];
            b2r[jj] = b2s[j];
        }
        #pragma unroll
        for (int e = 0; e < WROWS/4; ++e) {
            const int r = e*4 + rb;
            const float4 q = *(const float4*)qsw[r];
            float4 o;
            o.x = fmaf(q.x,w2r[0][0], fmaf(q.y,w2r[0][1], fmaf(q.z,w2r[0][2], fmaf(q.w,w2r[0][3], b2r[0]))));
            o.y = fmaf(q.x,w2r[1][0], fmaf(q.y,w2r[1][1], fmaf(q.z,w2r[1][2], fmaf(q.w,w2r[1][3], b2r[1]))));
            o.z = fmaf(q.x,w2r[2][0], fmaf(q.y,w2r[2][1], fmaf(q.z,w2r[2][2], fmaf(q.w,w2r[2][3], b2r[2]))));
            o.w = fmaf(q.x,w2r[3][0], fmaf(q.y,w2r[3][1], fmaf(q.z,w2r[3][2], fmaf(q.w,w2r[3][3], b2r[3]))));
            ((float4*)(out + (size_t)(wrow + r) * DOUT))[j4] = o;
        }
    }
}

extern "C" void kernel_launch(void* const* d_in, const int* in_sizes, int n_in,
                              void* d_out, int out_size, void* d_ws, size_t ws_size,
                              hipStream_t stream) {
    const float* x  = (const float*)d_in[0];
    const float* W1 = (const float*)d_in[1];
    const float* b1 = (const float*)d_in[2];
    const float* wt = (const float*)d_in[3];
    const float* W2 = (const float*)d_in[4];
    const float* b2 = (const float*)d_in[5];
    float* out = (float*)d_out;
    const int B = in_sizes[0] / DIN;        // 131072
    qp_fused<<<B / (WROWS * 4), TPB, 0, stream>>>(x, W1, b1, wt, W2, b2, out);
}

// Round 9
// 35.604 us; speedup vs baseline: 1.1782x; 1.1782x over previous
//
#include <hip/hip_runtime.h>
#include <math.h>

#define NQ 4
#define DIN 256
#define DOUT 64
#define NLAYER 2
#define TPB 256
#define WROWS 64            // rows per wave; block = 4 waves = 256 rows; grid = 512
#define NIT (WROWS/2)       // 32 iterations, 2 rows per wave-iteration
#define PF 3                // prefetch depth (iterations ahead)

typedef float nt4 __attribute__((ext_vector_type(4)));   // clang vector for NT builtins

__device__ __forceinline__ float tanh_fast(float y) {
    float e = __expf(2.0f * y);
    return 1.0f - 2.0f / (e + 1.0f);
}

__global__ __launch_bounds__(TPB, 2) void qp_fused(
    const float* __restrict__ x,  const float* __restrict__ W1,
    const float* __restrict__ b1, const float* __restrict__ wts,
    const float* __restrict__ W2, const float* __restrict__ b2,
    float* __restrict__ out)
{
    __shared__ __align__(16) float fs[4][WROWS][NQ];  // wave-private f tiles, 4 KB
    __shared__ __align__(16) float qs[4][WROWS][NQ];  // wave-private q tiles, 4 KB
    __shared__ __align__(16) float w2s[DOUT][NQ];     // 1 KB
    __shared__ __align__(16) float us[8][8];          // Rot gates
    __shared__ float b2s[DOUT];

    const int t = threadIdx.x;
    const int wave = t >> 6, lane = t & 63;
    const int half = lane >> 5;          // which of the wave's 2 rows per iter
    const int cl   = lane & 31;          // float4 chunk index within row half
    const int qsel = lane & 3;

    // ---- stage shared constants; the ONLY block-wide barrier
    if (t < 64) {
        ((float4*)&w2s[0][0])[t] = ((const float4*)W2)[t];
        b2s[t] = b2[t];
    }
    if (t < 8) {
        const float phi = wts[t*3 + 0], th = wts[t*3 + 1], om = wts[t*3 + 2];
        float sth, cth; sincosf(0.5f*th, &sth, &cth);
        float sp, cp;   sincosf(0.5f*(phi+om), &sp, &cp);
        float sm, cm;   sincosf(0.5f*(phi-om), &sm, &cm);
        us[t][0] =  cth*cp; us[t][1] = -cth*sp;
        us[t][2] = -sth*cm; us[t][3] = -sth*sm;
        us[t][4] =  sth*cm; us[t][5] = -sth*sm;
        us[t][6] =  cth*cp; us[t][7] =  cth*sp;
    }
    __syncthreads();

    const int wrow = (blockIdx.x * 4 + wave) * WROWS;  // wave's first row
    float (* __restrict__ fsw)[NQ] = fs[wave];
    float (* __restrict__ qsw)[NQ] = qs[wave];

    // ---- phase 1: f = pi*tanh(x@W1^T+b1); 32 lanes/row; NT streaming loads
    {
        float4 w[4][2];
        #pragma unroll
        for (int q = 0; q < 4; ++q) {
            w[q][0] = ((const float4*)W1)[q*64 + cl];
            w[q][1] = ((const float4*)W1)[q*64 + 32 + cl];
        }
        const float4 bv = *(const float4*)b1;
        const float bsel = (qsel==0)?bv.x:(qsel==1)?bv.y:(qsel==2)?bv.z:bv.w;

        const int row0 = wrow + half;               // + it*2

        nt4 buf[PF+1][2];                           // ring, statically indexed
        #pragma unroll
        for (int k = 0; k < PF; ++k) {
            const nt4* xn = (const nt4*)(x + (size_t)(row0 + k*2) * DIN);
            buf[k][0] = __builtin_nontemporal_load(xn + cl);
            buf[k][1] = __builtin_nontemporal_load(xn + 32 + cl);
        }

        #pragma unroll
        for (int it = 0; it < NIT; ++it) {
            if (it + PF < NIT) {
                const nt4* xn = (const nt4*)(x + (size_t)(row0 + (it+PF)*2) * DIN);
                buf[(it+PF)&PF][0] = __builtin_nontemporal_load(xn + cl);
                buf[(it+PF)&PF][1] = __builtin_nontemporal_load(xn + 32 + cl);
            }
            const nt4 xv0 = buf[it&PF][0];
            const nt4 xv1 = buf[it&PF][1];

            float a0, a1, a2, a3;
            a0 = fmaf(xv0.x,w[0][0].x, fmaf(xv0.y,w[0][0].y, fmaf(xv0.z,w[0][0].z, xv0.w*w[0][0].w)));
            a1 = fmaf(xv0.x,w[1][0].x, fmaf(xv0.y,w[1][0].y, fmaf(xv0.z,w[1][0].z, xv0.w*w[1][0].w)));
            a2 = fmaf(xv0.x,w[2][0].x, fmaf(xv0.y,w[2][0].y, fmaf(xv0.z,w[2][0].z, xv0.w*w[2][0].w)));
            a3 = fmaf(xv0.x,w[3][0].x, fmaf(xv0.y,w[3][0].y, fmaf(xv0.z,w[3][0].z, xv0.w*w[3][0].w)));
            a0 = fmaf(xv1.x,w[0][1].x, fmaf(xv1.y,w[0][1].y, fmaf(xv1.z,w[0][1].z, fmaf(xv1.w,w[0][1].w, a0))));
            a1 = fmaf(xv1.x,w[1][1].x, fmaf(xv1.y,w[1][1].y, fmaf(xv1.z,w[1][1].z, fmaf(xv1.w,w[1][1].w, a1))));
            a2 = fmaf(xv1.x,w[2][1].x, fmaf(xv1.y,w[2][1].y, fmaf(xv1.z,w[2][1].z, fmaf(xv1.w,w[2][1].w, a2))));
            a3 = fmaf(xv1.x,w[3][1].x, fmaf(xv1.y,w[3][1].y, fmaf(xv1.z,w[3][1].z, fmaf(xv1.w,w[3][1].w, a3))));

            a0 += __shfl_xor(a0, 1, 64);  a1 += __shfl_xor(a1, 1, 64);
            a2 += __shfl_xor(a2, 1, 64);  a3 += __shfl_xor(a3, 1, 64);
            a0 += __shfl_xor(a0, 2, 64);  a1 += __shfl_xor(a1, 2, 64);
            a2 += __shfl_xor(a2, 2, 64);  a3 += __shfl_xor(a3, 2, 64);
            float v = (qsel==0)?a0:(qsel==1)?a1:(qsel==2)?a2:a3;
            v += __shfl_xor(v, 4, 64);
            v += __shfl_xor(v, 8, 64);
            v += __shfl_xor(v, 16, 64);

            if (cl < 4) {
                const float PI = 3.14159265358979f;
                fsw[it*2 + half][qsel] = PI * tanh_fast(v + bsel);
            }
        }
    }
    // same-wave LDS producer->consumer: compiler inserts lgkmcnt wait; no barrier

    // ---- phase 2: 4-qubit circuit, one row per lane (all 64 lanes active)
    {
        const float4 fv = *(const float4*)fsw[lane];
        const float fq[4] = {fv.x, fv.y, fv.z, fv.w};
        const float IS2 = 0.70710678118654752f;
        float vr[4][2], vi[4][2];
        #pragma unroll
        for (int i = 0; i < 4; ++i) {
            const float fi = fq[i];
            const float f2 = fi*fi;
            const float ca = rsqrtf(1.0f + f2);
            const float ch = sqrtf(0.5f*(1.0f + ca));
            const float sh = copysignf(sqrtf(fmaxf(0.5f*(1.0f - ca), 0.0f)), fi);
            const float cb = rsqrtf(1.0f + f2*f2);
            const float cbh = sqrtf(0.5f*(1.0f + cb));
            const float sbh = sqrtf(fmaxf(0.5f*(1.0f - cb), 0.0f));
            const float u0 = (ch - sh) * IS2;
            const float u1 = (ch + sh) * IS2;
            vr[i][0] = u0 * cbh;  vi[i][0] = -u0 * sbh;
            vr[i][1] = u1 * cbh;  vi[i][1] =  u1 * sbh;
        }
        float ar[16], ai[16];
        #pragma unroll
        for (int i0 = 0; i0 < 2; ++i0)
        #pragma unroll
        for (int i1 = 0; i1 < 2; ++i1) {
            const float pr  = vr[0][i0]*vr[1][i1] - vi[0][i0]*vi[1][i1];
            const float pim = vr[0][i0]*vi[1][i1] + vi[0][i0]*vr[1][i1];
            #pragma unroll
            for (int i2 = 0; i2 < 2; ++i2)
            #pragma unroll
            for (int i3 = 0; i3 < 2; ++i3) {
                const float qr  = vr[2][i2]*vr[3][i3] - vi[2][i2]*vi[3][i3];
                const float qim = vr[2][i2]*vi[3][i3] + vi[2][i2]*vr[3][i3];
                const int idx = i0*8 + i1*4 + i2*2 + i3;
                ar[idx] = pr*qr - pim*qim;
                ai[idx] = pr*qim + pim*qr;
            }
        }
        #pragma unroll
        for (int l = 0; l < NLAYER; ++l) {
            constexpr int cpairs[8][2] = {{0,1},{1,2},{2,3},{3,0},{0,2},{1,3},{2,0},{3,1}};
            #pragma unroll
            for (int g = 0; g < 8; ++g) {
                const int bc = 8 >> cpairs[g][0];
                const int bt = 8 >> cpairs[g][1];
                #pragma unroll
                for (int m = 0; m < 16; ++m) {
                    if ((m & bc) && !(m & bt)) {
                        const int m2 = m | bt;
                        float tr = ar[m]; ar[m] = ar[m2]; ar[m2] = tr;
                        float ti = ai[m]; ai[m] = ai[m2]; ai[m2] = ti;
                    }
                }
            }
            #pragma unroll
            for (int i = 0; i < 4; ++i) {
                const float* u = &us[l*4 + i][0];
                const float u00r=u[0], u00i=u[1], u01r=u[2], u01i=u[3];
                const float u10r=u[4], u10i=u[5], u11r=u[6], u11i=u[7];
                const int bq = 8 >> i;
                #pragma unroll
                for (int m = 0; m < 16; ++m) {
                    if (!(m & bq)) {
                        const int m2 = m | bq;
                        const float a0r=ar[m], a0i=ai[m], a1r=ar[m2], a1i=ai[m2];
                        ar[m]  = u00r*a0r - u00i*a0i + u01r*a1r - u01i*a1i;
                        ai[m]  = u00r*a0i + u00i*a0r + u01r*a1i + u01i*a1r;
                        ar[m2] = u10r*a0r - u10i*a0i + u11r*a1r - u11i*a1i;
                        ai[m2] = u10r*a0i + u10i*a0r + u11r*a1i + u11i*a1r;
                    }
                }
            }
        }
        float z0=0.f, z1=0.f, z2=0.f, z3=0.f;
        #pragma unroll
        for (int m = 0; m < 16; ++m) {
            const float p = ar[m]*ar[m] + ai[m]*ai[m];
            z0 += (m & 8) ? -p : p;
            z1 += (m & 4) ? -p : p;
            z2 += (m & 2) ? -p : p;
            z3 += (m & 1) ? -p : p;
        }
        float4 qv; qv.x=z0; qv.y=z1; qv.z=z2; qv.w=z3;
        *(float4*)qsw[lane] = qv;
    }

    // ---- phase 3: out = q @ W2^T + b2, NT streaming stores
    {
        const int j4 = lane & 15;        // output float4-column
        const int rb = lane >> 4;        // 0..3 row subgroup
        float w2r[4][4], b2r[4];
        #pragma unroll
        for (int jj = 0; jj < 4; ++jj) {
            const int j = j4*4 + jj;
            #pragma unroll
            for (int i = 0; i < 4; ++i) w2r[jj][i] = w2s[j][i];
            b2r[jj] = b2s[j];
        }
        #pragma unroll
        for (int e = 0; e < WROWS/4; ++e) {
            const int r = e*4 + rb;
            const float4 q = *(const float4*)qsw[r];
            nt4 o;
            o.x = fmaf(q.x,w2r[0][0], fmaf(q.y,w2r[0][1], fmaf(q.z,w2r[0][2], fmaf(q.w,w2r[0][3], b2r[0]))));
            o.y = fmaf(q.x,w2r[1][0], fmaf(q.y,w2r[1][1], fmaf(q.z,w2r[1][2], fmaf(q.w,w2r[1][3], b2r[1]))));
            o.z = fmaf(q.x,w2r[2][0], fmaf(q.y,w2r[2][1], fmaf(q.z,w2r[2][2], fmaf(q.w,w2r[2][3], b2r[2]))));
            o.w = fmaf(q.x,w2r[3][0], fmaf(q.y,w2r[3][1], fmaf(q.z,w2r[3][2], fmaf(q.w,w2r[3][3], b2r[3]))));
            __builtin_nontemporal_store(o, (nt4*)(out + (size_t)(wrow + r) * DOUT) + j4);
        }
    }
}

extern "C" void kernel_launch(void* const* d_in, const int* in_sizes, int n_in,
                              void* d_out, int out_size, void* d_ws, size_t ws_size,
                              hipStream_t stream) {
    const float* x  = (const float*)d_in[0];
    const float* W1 = (const float*)d_in[1];
    const float* b1 = (const float*)d_in[2];
    const float* wt = (const float*)d_in[3];
    const float* W2 = (const float*)d_in[4];
    const float* b2 = (const float*)d_in[5];
    float* out = (float*)d_out;
    const int B = in_sizes[0] / DIN;        // 131072
    qp_fused<<<B / (WROWS * 4), TPB, 0, stream>>>(x, W1, b1, wt, W2, b2, out);
}